// Round 4
// baseline (13018.996 us; speedup 1.0000x reference)
//
#include <hip/hip_runtime.h>
#include <stdint.h>

typedef unsigned short u16;
typedef __attribute__((ext_vector_type(8))) short short8;
typedef __attribute__((ext_vector_type(4))) float f32x4;
typedef __attribute__((ext_vector_type(4))) unsigned u32x4;

#define T_SEQ 1024
#define TP1   1025
#define HDIM  1024
#define NG    3072

__device__ __forceinline__ u16 f2bf(float f) {
  unsigned u = __float_as_uint(f);
  u += 0x7FFF + ((u >> 16) & 1);
  return (u16)(u >> 16);
}
__device__ __forceinline__ float bf2f(unsigned h) {
  return __uint_as_float(h << 16);
}
__device__ __forceinline__ unsigned ldA(const unsigned* p) {
  return __hip_atomic_load(p, __ATOMIC_RELAXED, __HIP_MEMORY_SCOPE_AGENT);
}
__device__ __forceinline__ void stA(unsigned* p, unsigned v) {
  __hip_atomic_store(p, v, __ATOMIC_RELAXED, __HIP_MEMORY_SCOPE_AGENT);
}

// async global->LDS, 16B per lane (GEMM staging only)
__device__ __forceinline__ void gld16(void* lds, const void* g) {
  __builtin_amdgcn_global_load_lds(
      (const __attribute__((address_space(1))) unsigned*)g,
      (__attribute__((address_space(3))) unsigned*)lds,
      16, 0, 0);
}

// Stage one tagged h-row slice: thread covers row b (lrow given), 64 j's as 4 groups
// of 16 (j = g*256 + c*16 + i). Strips tags, packs bf16 pairs, writes LDS.
__device__ __forceinline__ void stage64(const unsigned* __restrict__ grow,
                                        u16* __restrict__ lrow, int c, unsigned tag) {
#pragma unroll
  for (int half = 0; half < 2; ++half) {
    unsigned w[32];
#pragma unroll
    for (int k = 0; k < 32; ++k)
      w[k] = ldA(grow + (half * 2 + (k >> 4)) * 256 + c * 16 + (k & 15));
#pragma unroll
    for (int k = 0; k < 32; ++k)
      while ((w[k] >> 16) != tag)
        w[k] = ldA(grow + (half * 2 + (k >> 4)) * 256 + c * 16 + (k & 15));
#pragma unroll
    for (int g = 0; g < 2; ++g) {
      unsigned p[8];
#pragma unroll
      for (int i = 0; i < 8; ++i)
        p[i] = (w[g * 16 + 2 * i] & 0xFFFFu) | (w[g * 16 + 2 * i + 1] << 16);
      u32x4* dst = (u32x4*)(lrow + (half * 2 + g) * 256 + c * 16);
      dst[0] = (u32x4){p[0], p[1], p[2], p[3]};
      dst[1] = (u32x4){p[4], p[5], p[6], p[7]};
    }
  }
}

// ---------------- prep: cast 5 weight tensors fp32->bf16 ------------------------
__global__ void cast5_kernel(const float* __restrict__ s0, const float* __restrict__ s1,
                             const float* __restrict__ s2, const float* __restrict__ s3,
                             const float* __restrict__ s4,
                             u16* __restrict__ d0, u16* __restrict__ d1,
                             u16* __restrict__ d2, u16* __restrict__ d3,
                             u16* __restrict__ d4) {
  int bid = blockIdx.x;
  const float* s; u16* d; size_t base;
  if (bid < 3072)       { s = s0; d = d0; base = (size_t)bid * 1024; }
  else if (bid < 6144)  { s = s1; d = d1; base = (size_t)(bid - 3072) * 1024; }
  else if (bid < 9216)  { s = s2; d = d2; base = (size_t)(bid - 6144) * 1024; }
  else if (bid < 12288) { s = s3; d = d3; base = (size_t)(bid - 9216) * 1024; }
  else                  { s = s4; d = d4; base = (size_t)(bid - 12288) * 1024; }
  size_t i = base + (size_t)threadIdx.x * 4;
  float4 v = *(const float4*)(s + i);
  unsigned lo = (unsigned)f2bf(v.x) | ((unsigned)f2bf(v.y) << 16);
  unsigned hi = (unsigned)f2bf(v.z) | ((unsigned)f2bf(v.w) << 16);
  uint2 o; o.x = lo; o.y = hi;
  *(uint2*)(d + i) = o;
}

// ---------------- embedding gather + cast to bf16 ------------------------------
__global__ void gather_cast_kernel(const int* __restrict__ tokens,
                                   const float* __restrict__ emb,
                                   u16* __restrict__ xbf) {
  int row = blockIdx.x;                 // 0..16383  (= b*T + t)
  int tok = tokens[row];
  const float4* src = (const float4*)(emb + (size_t)tok * HDIM);
  float4 v = src[threadIdx.x];
  unsigned lo = (unsigned)f2bf(v.x) | ((unsigned)f2bf(v.y) << 16);
  unsigned hi = (unsigned)f2bf(v.z) | ((unsigned)f2bf(v.w) << 16);
  uint2 o; o.x = lo; o.y = hi;
  *(uint2*)(xbf + (size_t)row * HDIM + (size_t)threadIdx.x * 4) = o;
}

// ---------------- bf16 MFMA GEMM, C[m,n] = sum_k A[m,k]*Bt[n,k] -----------------
template <bool OUT_BF16, bool A_REMAP, bool ADD_BIAS>
__global__ __launch_bounds__(256)
void gemm_bt(const u16* __restrict__ A, const u16* __restrict__ Bt,
             void* __restrict__ Cout, const float* __restrict__ bias,
             int M, int N) {
  const int K = 1024;
  __shared__ u16 As[128 * 32];
  __shared__ u16 Bs[128 * 32];
  const int tid = threadIdx.x;
  const int wave = tid >> 6, lane = tid & 63;
  const int quad = lane >> 4, l16 = lane & 15;
  const int wm = (wave & 1) * 64, wn = (wave >> 1) * 64;
  const int m0 = blockIdx.x * 128, n0 = blockIdx.y * 128;
  const int srow = tid >> 2, scol = (tid & 3) * 8;

  size_t arow0, arow1;
  {
    int r0 = m0 + srow, r1 = m0 + 64 + srow;
    if (A_REMAP) {
      arow0 = (size_t)((r0 >> 10) * TP1 + (r0 & 1023) + 1);
      arow1 = (size_t)((r1 >> 10) * TP1 + (r1 & 1023) + 1);
    } else { arow0 = (size_t)r0; arow1 = (size_t)r1; }
  }
  const size_t brow0 = (size_t)(n0 + srow), brow1 = (size_t)(n0 + 64 + srow);

  f32x4 acc[4][4] = {};

  for (int kk = 0; kk < K; kk += 32) {
    __syncthreads();
    gld16(&As[srow * 32 + scol],        A + arow0 * K + kk + scol);
    gld16(&As[(64 + srow) * 32 + scol], A + arow1 * K + kk + scol);
    gld16(&Bs[srow * 32 + scol],        Bt + brow0 * K + kk + scol);
    gld16(&Bs[(64 + srow) * 32 + scol], Bt + brow1 * K + kk + scol);
    __syncthreads();
    short8 af[4], bfr[4];
#pragma unroll
    for (int mt = 0; mt < 4; ++mt)
      af[mt] = *(const short8*)&As[(wm + mt * 16 + l16) * 32 + quad * 8];
#pragma unroll
    for (int nt = 0; nt < 4; ++nt)
      bfr[nt] = *(const short8*)&Bs[(wn + nt * 16 + l16) * 32 + quad * 8];
#pragma unroll
    for (int mt = 0; mt < 4; ++mt)
#pragma unroll
      for (int nt = 0; nt < 4; ++nt)
        acc[mt][nt] = __builtin_amdgcn_mfma_f32_16x16x32_bf16(af[mt], bfr[nt], acc[mt][nt], 0, 0, 0);
  }
#pragma unroll
  for (int mt = 0; mt < 4; ++mt) {
#pragma unroll
    for (int nt = 0; nt < 4; ++nt) {
#pragma unroll
      for (int r = 0; r < 4; ++r) {
        int m = m0 + wm + mt * 16 + quad * 4 + r;
        int n = n0 + wn + nt * 16 + l16;
        float v = acc[mt][nt][r];
        if (ADD_BIAS) v += bias[n];
        if (OUT_BF16) ((u16*)Cout)[(size_t)m * N + n] = f2bf(v);
        else          ((float*)Cout)[(size_t)m * N + n] = v;
      }
    }
  }
}

// ---------------- 3-stage pipelined persistent scan, 192 WGs --------------------
// Group 0 (WG 0..63):    L0  — h1 recurrence (gx0 precomputed).
// Group 1 (WG 64..127):  GX1 — gx1[t] = h1[t] @ Wih1^T, into 16-slot tagged ring.
// Group 2 (WG 128..191): L1  — h2 recurrence from gx1 ring + Whh1.
// All transport is self-validating tagged words: u32 = bf16 | (tag<<16).
// No fences, no flags, no drains; relaxed agent loads/stores only.
__global__ __launch_bounds__(256, 1)
void fused_scan_kernel(const u16* __restrict__ gx0,
                       unsigned* __restrict__ h1tag,   // [16][1025][1024] u32
                       unsigned* __restrict__ h2tag,   // [16][1025][1024] u32
                       unsigned* __restrict__ gx1ring, // [16][16][3072] u32
                       u16* __restrict__ h2seq,        // [16][1025][1024] bf16 packed
                       const u16* __restrict__ Whh0, const u16* __restrict__ Wih1,
                       const u16* __restrict__ Whh1,
                       const float* __restrict__ bih0, const float* __restrict__ bhh0,
                       const float* __restrict__ bih1, const float* __restrict__ bhh1) {
  const int tid = threadIdx.x;
  const int wave = tid >> 6, lane = tid & 63;
  const int quad = lane >> 4, l16 = lane & 15;
  const int kbase = wave * 256;
  const int b = tid >> 4, c = tid & 15;      // this thread's (batch, j-within-slice)
  const int grp = blockIdx.x >> 6;
  const int wg = blockIdx.x & 63, j0 = wg * 16;

  __shared__ u16 hs[16 * 1032];
  __shared__ float part[4][3][256];
  __shared__ float biasS[2][3][16];

  // register-resident weight fragments for this group's matvec
  const u16* W = (grp == 0) ? Whh0 : (grp == 1) ? Wih1 : Whh1;
  short8 wf[3][8];
#pragma unroll
  for (int g = 0; g < 3; ++g)
#pragma unroll
    for (int s = 0; s < 8; ++s)
      wf[g][s] = *(const short8*)&W[(size_t)(g * 1024 + j0 + l16) * 1024 + kbase + s * 32 + quad * 8];

  if (grp != 1 && tid < 96) {
    int a = tid / 48, rem = tid % 48, g = rem >> 4, jl = rem & 15;
    const float* bi = (grp == 0) ? (a ? bhh0 : bih0) : (a ? bhh1 : bih1);
    biasS[a][g][jl] = bi[g * 1024 + j0 + jl];
  }

  if (grp == 0) {
    // ---------- L0 ----------
    stA(h1tag + ((size_t)b * TP1 + 0) * HDIM + j0 + c, 1u << 16);  // h_{-1}=0, tag 1
    float hprev = 0.f;
    for (int t = 0; t < T_SEQ; ++t) {
      const u16* gxp = gx0 + ((size_t)(b * T_SEQ + t)) * NG + j0 + c;
      u16 g0 = gxp[0], g1 = gxp[1024], g2 = gxp[2048];
      stage64(h1tag + ((size_t)b * TP1 + t) * HDIM, hs + b * 1032, c, (unsigned)(t + 1));
      __syncthreads();
      f32x4 a0 = {0.f,0.f,0.f,0.f}, a1 = {0.f,0.f,0.f,0.f}, a2 = {0.f,0.f,0.f,0.f};
#pragma unroll
      for (int s = 0; s < 8; ++s) {
        short8 afr = *(const short8*)&hs[l16 * 1032 + kbase + s * 32 + quad * 8];
        a0 = __builtin_amdgcn_mfma_f32_16x16x32_bf16(afr, wf[0][s], a0, 0, 0, 0);
        a1 = __builtin_amdgcn_mfma_f32_16x16x32_bf16(afr, wf[1][s], a1, 0, 0, 0);
        a2 = __builtin_amdgcn_mfma_f32_16x16x32_bf16(afr, wf[2][s], a2, 0, 0, 0);
      }
#pragma unroll
      for (int r = 0; r < 4; ++r) {
        int o = (quad * 4 + r) * 16 + l16;
        part[wave][0][o] = a0[r]; part[wave][1][o] = a1[r]; part[wave][2][o] = a2[r];
      }
      __syncthreads();
      float ghr = part[0][0][tid] + part[1][0][tid] + part[2][0][tid] + part[3][0][tid] + biasS[1][0][c];
      float ghz = part[0][1][tid] + part[1][1][tid] + part[2][1][tid] + part[3][1][tid] + biasS[1][1][c];
      float ghn = part[0][2][tid] + part[1][2][tid] + part[2][2][tid] + part[3][2][tid] + biasS[1][2][c];
      float xr = bf2f(g0) + biasS[0][0][c] + ghr;
      float xz = bf2f(g1) + biasS[0][1][c] + ghz;
      float xn = bf2f(g2) + biasS[0][2][c];
      float r_ = 1.f / (1.f + __expf(-xr));
      float z_ = 1.f / (1.f + __expf(-xz));
      float pre = fminf(fmaxf(xn + r_ * ghn, -15.f), 15.f);
      float e2 = __expf(2.f * pre);
      float n_ = (e2 - 1.f) / (e2 + 1.f);
      float hn = (1.f - z_) * n_ + z_ * hprev;
      hprev = hn;
      stA(h1tag + ((size_t)b * TP1 + t + 1) * HDIM + j0 + c,
          (unsigned)f2bf(hn) | ((unsigned)(t + 2) << 16));
    }
  } else if (grp == 1) {
    // ---------- GX1 ----------
    for (int t = 0; t < T_SEQ; ++t) {
      if (t >= 14) {  // ring backpressure: L1 must have finished step t-14
        const unsigned* bp = h2tag + ((size_t)b * TP1 + (t - 13)) * HDIM + j0 + c;
        while ((ldA(bp) >> 16) != (unsigned)(t - 12)) {}
      }
      stage64(h1tag + ((size_t)b * TP1 + t + 1) * HDIM, hs + b * 1032, c, (unsigned)(t + 2));
      __syncthreads();
      f32x4 a0 = {0.f,0.f,0.f,0.f}, a1 = {0.f,0.f,0.f,0.f}, a2 = {0.f,0.f,0.f,0.f};
#pragma unroll
      for (int s = 0; s < 8; ++s) {
        short8 afr = *(const short8*)&hs[l16 * 1032 + kbase + s * 32 + quad * 8];
        a0 = __builtin_amdgcn_mfma_f32_16x16x32_bf16(afr, wf[0][s], a0, 0, 0, 0);
        a1 = __builtin_amdgcn_mfma_f32_16x16x32_bf16(afr, wf[1][s], a1, 0, 0, 0);
        a2 = __builtin_amdgcn_mfma_f32_16x16x32_bf16(afr, wf[2][s], a2, 0, 0, 0);
      }
#pragma unroll
      for (int r = 0; r < 4; ++r) {
        int o = (quad * 4 + r) * 16 + l16;
        part[wave][0][o] = a0[r]; part[wave][1][o] = a1[r]; part[wave][2][o] = a2[r];
      }
      __syncthreads();
      unsigned tg = (unsigned)(t + 1) << 16;
      unsigned* ring = gx1ring + ((size_t)b * 16 + (t & 15)) * NG + j0 + c;
#pragma unroll
      for (int g = 0; g < 3; ++g) {
        float v = part[0][g][tid] + part[1][g][tid] + part[2][g][tid] + part[3][g][tid];
        stA(ring + g * 1024, (unsigned)f2bf(v) | tg);
      }
      __syncthreads();  // part[] reuse guard across iterations
    }
  } else {
    // ---------- L1 ----------
    stA(h2tag + ((size_t)b * TP1 + 0) * HDIM + j0 + c, 1u << 16);
    float hprev = 0.f;
    for (int t = 0; t < T_SEQ; ++t) {
      unsigned tg = (unsigned)(t + 1);
      const unsigned* ring = gx1ring + ((size_t)b * 16 + (t & 15)) * NG + j0 + c;
      unsigned q0 = ldA(ring), q1 = ldA(ring + 1024), q2 = ldA(ring + 2048);
      while ((q0 >> 16) != tg) q0 = ldA(ring);
      while ((q1 >> 16) != tg) q1 = ldA(ring + 1024);
      while ((q2 >> 16) != tg) q2 = ldA(ring + 2048);
      stage64(h2tag + ((size_t)b * TP1 + t) * HDIM, hs + b * 1032, c, (unsigned)(t + 1));
      __syncthreads();
      f32x4 a0 = {0.f,0.f,0.f,0.f}, a1 = {0.f,0.f,0.f,0.f}, a2 = {0.f,0.f,0.f,0.f};
#pragma unroll
      for (int s = 0; s < 8; ++s) {
        short8 afr = *(const short8*)&hs[l16 * 1032 + kbase + s * 32 + quad * 8];
        a0 = __builtin_amdgcn_mfma_f32_16x16x32_bf16(afr, wf[0][s], a0, 0, 0, 0);
        a1 = __builtin_amdgcn_mfma_f32_16x16x32_bf16(afr, wf[1][s], a1, 0, 0, 0);
        a2 = __builtin_amdgcn_mfma_f32_16x16x32_bf16(afr, wf[2][s], a2, 0, 0, 0);
      }
#pragma unroll
      for (int r = 0; r < 4; ++r) {
        int o = (quad * 4 + r) * 16 + l16;
        part[wave][0][o] = a0[r]; part[wave][1][o] = a1[r]; part[wave][2][o] = a2[r];
      }
      __syncthreads();
      float shr = part[0][0][tid] + part[1][0][tid] + part[2][0][tid] + part[3][0][tid] + biasS[1][0][c];
      float shz = part[0][1][tid] + part[1][1][tid] + part[2][1][tid] + part[3][1][tid] + biasS[1][1][c];
      float shn = part[0][2][tid] + part[1][2][tid] + part[2][2][tid] + part[3][2][tid] + biasS[1][2][c];
      float xr = bf2f(q0 & 0xFFFFu) + biasS[0][0][c] + shr;
      float xz = bf2f(q1 & 0xFFFFu) + biasS[0][1][c] + shz;
      float xn = bf2f(q2 & 0xFFFFu) + biasS[0][2][c];
      float r_ = 1.f / (1.f + __expf(-xr));
      float z_ = 1.f / (1.f + __expf(-xz));
      float pre = fminf(fmaxf(xn + r_ * shn, -15.f), 15.f);
      float e2 = __expf(2.f * pre);
      float n_ = (e2 - 1.f) / (e2 + 1.f);
      float hn = (1.f - z_) * n_ + z_ * hprev;
      hprev = hn;
      stA(h2tag + ((size_t)b * TP1 + t + 1) * HDIM + j0 + c,
          (unsigned)f2bf(hn) | ((unsigned)(t + 2) << 16));
      // packed h2 for the head GEMM (plain store; flushed at dispatch end)
      unsigned mine = (unsigned)f2bf(hn);
      unsigned other = __shfl_xor(mine, 1);
      if ((tid & 1) == 0)
        *(unsigned*)(h2seq + ((size_t)b * TP1 + t + 1) * HDIM + j0 + c) = mine | (other << 16);
    }
  }
}

// ---------------- log_softmax over axis=1 (T): grid (16 b, 8 cgroups) ----------
__global__ void logsoftmax_kernel(float* __restrict__ out) {
  int b = blockIdx.x, cg = blockIdx.y;
  int ci = threadIdx.x & 15, ts = threadIdx.x >> 4;
  int c = cg * 16 + ci;
  float m = -1e30f, s = 0.f;
  for (int t = ts; t < T_SEQ; t += 16) {
    float v = out[((size_t)b * T_SEQ + t) * 128 + c];
    if (v > m) { s = s * __expf(m - v) + 1.f; m = v; }
    else s += __expf(v - m);
  }
  __shared__ float mS[16][16], sS[16][16];
  mS[ts][ci] = m; sS[ts][ci] = s;
  __syncthreads();
  if (ts == 0) {
    float M = mS[0][ci], S = sS[0][ci];
#pragma unroll
    for (int k = 1; k < 16; ++k) {
      float m2 = mS[k][ci], s2 = sS[k][ci];
      float nm = fmaxf(M, m2);
      S = S * __expf(M - nm) + s2 * __expf(m2 - nm);
      M = nm;
    }
    sS[0][ci] = M + logf(S);
  }
  __syncthreads();
  float lsd = sS[0][ci];
  for (int t = ts; t < T_SEQ; t += 16) {
    size_t i = ((size_t)b * T_SEQ + t) * 128 + c;
    out[i] -= lsd;
  }
}

// --------------------------------------------------------------------------------
extern "C" void kernel_launch(void* const* d_in, const int* in_sizes, int n_in,
                              void* d_out, int out_size, void* d_ws, size_t ws_size,
                              hipStream_t stream) {
  const int*   tokens = (const int*)d_in[0];
  const float* emb  = (const float*)d_in[1];
  const float* Wih0 = (const float*)d_in[2];
  const float* Whh0 = (const float*)d_in[3];
  const float* bih0 = (const float*)d_in[4];
  const float* bhh0 = (const float*)d_in[5];
  const float* Wih1 = (const float*)d_in[6];
  const float* Whh1 = (const float*)d_in[7];
  const float* bih1 = (const float*)d_in[8];
  const float* bhh1 = (const float*)d_in[9];
  const float* Wlin = (const float*)d_in[10];
  const float* blin = (const float*)d_in[11];
  float* out = (float*)d_out;

  uint8_t* ws = (uint8_t*)d_ws;
  size_t off = 0;
  auto alloc = [&](size_t bytes) -> void* {
    void* p = ws + off;
    off += (bytes + 255) & ~(size_t)255;
    return p;
  };
  unsigned* h1tag = (unsigned*)alloc((size_t)16 * TP1 * HDIM * 4);   // 67 MB
  unsigned* h2tag = (unsigned*)alloc((size_t)16 * TP1 * HDIM * 4);   // 67 MB
  u16* gx0buf     = (u16*)alloc((size_t)16384 * NG * 2);             // 101 MB
  unsigned* gx1r  = (unsigned*)alloc((size_t)16 * 16 * NG * 4);      // 3.1 MB
  u16* h2seq      = (u16*)alloc((size_t)16 * TP1 * HDIM * 2);        // 33.6 MB (x-buf pre-scan)
  u16* wih0b = (u16*)alloc((size_t)NG * HDIM * 2);
  u16* whh0b = (u16*)alloc((size_t)NG * HDIM * 2);
  u16* wih1b = (u16*)alloc((size_t)NG * HDIM * 2);
  u16* whh1b = (u16*)alloc((size_t)NG * HDIM * 2);
  u16* wlinb = (u16*)alloc((size_t)128 * HDIM * 2);

  cast5_kernel<<<dim3(12416), dim3(256), 0, stream>>>(
      Wih0, Whh0, Wih1, Whh1, Wlin, wih0b, whh0b, wih1b, whh1b, wlinb);
  // x (bf16) into h2seq region (dead after gx0 GEMM; scan rewrites slots 1..1024)
  gather_cast_kernel<<<dim3(16384), dim3(256), 0, stream>>>(tokens, emb, h2seq);
  // gx0 = x @ W_ih0^T
  gemm_bt<true, false, false><<<dim3(128, 24), dim3(256), 0, stream>>>(
      h2seq, wih0b, gx0buf, nullptr, 16384, NG);
  // 3-stage pipelined scan: L0 | GX1 | L1
  fused_scan_kernel<<<dim3(192), dim3(256), 0, stream>>>(
      gx0buf, h1tag, h2tag, gx1r, h2seq, whh0b, wih1b, whh1b,
      bih0, bhh0, bih1, bhh1);
  // logits = h2 @ W_lin^T + b_lin -> d_out (fp32)
  gemm_bt<false, true, true><<<dim3(128, 1), dim3(256), 0, stream>>>(
      h2seq, wlinb, out, blin, 16384, 128);
  // log_softmax over T, in place
  logsoftmax_kernel<<<dim3(16, 8), dim3(256), 0, stream>>>(out);
}

// Round 5
// 5147.634 us; speedup vs baseline: 2.5291x; 2.5291x over previous
//
#include <hip/hip_runtime.h>
#include <stdint.h>

typedef unsigned short u16;
typedef __attribute__((ext_vector_type(8))) short short8;
typedef __attribute__((ext_vector_type(4))) float f32x4;

#define T_SEQ 1024
#define TP1   1025
#define HDIM  1024
#define NG    3072

__device__ __forceinline__ u16 f2bf(float f) {
  unsigned u = __float_as_uint(f);
  u += 0x7FFF + ((u >> 16) & 1);
  return (u16)(u >> 16);
}
__device__ __forceinline__ float bf2f(unsigned h) {
  return __uint_as_float(h << 16);
}
__device__ __forceinline__ unsigned ldA(const unsigned* p) {
  return __hip_atomic_load(p, __ATOMIC_RELAXED, __HIP_MEMORY_SCOPE_AGENT);
}
__device__ __forceinline__ void stA(unsigned* p, unsigned v) {
  __hip_atomic_store(p, v, __ATOMIC_RELAXED, __HIP_MEMORY_SCOPE_AGENT);
}
// wait vmcnt(0) only (exp=7, lgkm=15 ignored)
__device__ __forceinline__ void wait_vm0() { __builtin_amdgcn_s_waitcnt(0x0F70); }

// async global->LDS, 16B per lane; LDS dest = wave-uniform base + lane*16.
__device__ __forceinline__ void gld16(void* lds, const void* g) {
  __builtin_amdgcn_global_load_lds(
      (const __attribute__((address_space(1))) unsigned*)g,
      (__attribute__((address_space(3))) unsigned*)lds,
      16, 0, 0);
}

// ---------------- prep: cast 5 weight tensors fp32->bf16, zero 768 flags --------
__global__ void cast5_kernel(const float* __restrict__ s0, const float* __restrict__ s1,
                             const float* __restrict__ s2, const float* __restrict__ s3,
                             const float* __restrict__ s4,
                             u16* __restrict__ d0, u16* __restrict__ d1,
                             u16* __restrict__ d2, u16* __restrict__ d3,
                             u16* __restrict__ d4, unsigned* __restrict__ flags) {
  if (blockIdx.x == 0) {
    flags[threadIdx.x] = 0; flags[threadIdx.x + 256] = 0; flags[threadIdx.x + 512] = 0;
  }
  int bid = blockIdx.x;
  const float* s; u16* d; size_t base;
  if (bid < 3072)       { s = s0; d = d0; base = (size_t)bid * 1024; }
  else if (bid < 6144)  { s = s1; d = d1; base = (size_t)(bid - 3072) * 1024; }
  else if (bid < 9216)  { s = s2; d = d2; base = (size_t)(bid - 6144) * 1024; }
  else if (bid < 12288) { s = s3; d = d3; base = (size_t)(bid - 9216) * 1024; }
  else                  { s = s4; d = d4; base = (size_t)(bid - 12288) * 1024; }
  size_t i = base + (size_t)threadIdx.x * 4;
  float4 v = *(const float4*)(s + i);
  unsigned lo = (unsigned)f2bf(v.x) | ((unsigned)f2bf(v.y) << 16);
  unsigned hi = (unsigned)f2bf(v.z) | ((unsigned)f2bf(v.w) << 16);
  uint2 o; o.x = lo; o.y = hi;
  *(uint2*)(d + i) = o;
}

// ---------------- embedding gather + cast to bf16 ------------------------------
__global__ void gather_cast_kernel(const int* __restrict__ tokens,
                                   const float* __restrict__ emb,
                                   u16* __restrict__ xbf) {
  int row = blockIdx.x;
  int tok = tokens[row];
  const float4* src = (const float4*)(emb + (size_t)tok * HDIM);
  float4 v = src[threadIdx.x];
  unsigned lo = (unsigned)f2bf(v.x) | ((unsigned)f2bf(v.y) << 16);
  unsigned hi = (unsigned)f2bf(v.z) | ((unsigned)f2bf(v.w) << 16);
  uint2 o; o.x = lo; o.y = hi;
  *(uint2*)(xbf + (size_t)row * HDIM + (size_t)threadIdx.x * 4) = o;
}

// ---------------- bf16 MFMA GEMM, C[m,n] = sum_k A[m,k]*Bt[n,k] -----------------
template <bool OUT_BF16, bool A_REMAP, bool ADD_BIAS>
__global__ __launch_bounds__(256)
void gemm_bt(const u16* __restrict__ A, const u16* __restrict__ Bt,
             void* __restrict__ Cout, const float* __restrict__ bias,
             int M, int N) {
  const int K = 1024;
  __shared__ u16 As[128 * 32];
  __shared__ u16 Bs[128 * 32];
  const int tid = threadIdx.x;
  const int wave = tid >> 6, lane = tid & 63;
  const int quad = lane >> 4, l16 = lane & 15;
  const int wm = (wave & 1) * 64, wn = (wave >> 1) * 64;
  const int m0 = blockIdx.x * 128, n0 = blockIdx.y * 128;
  const int srow = tid >> 2, scol = (tid & 3) * 8;

  size_t arow0, arow1;
  {
    int r0 = m0 + srow, r1 = m0 + 64 + srow;
    if (A_REMAP) {
      arow0 = (size_t)((r0 >> 10) * TP1 + (r0 & 1023) + 1);
      arow1 = (size_t)((r1 >> 10) * TP1 + (r1 & 1023) + 1);
    } else { arow0 = (size_t)r0; arow1 = (size_t)r1; }
  }
  const size_t brow0 = (size_t)(n0 + srow), brow1 = (size_t)(n0 + 64 + srow);

  f32x4 acc[4][4] = {};

  for (int kk = 0; kk < K; kk += 32) {
    __syncthreads();
    gld16(&As[srow * 32 + scol],        A + arow0 * K + kk + scol);
    gld16(&As[(64 + srow) * 32 + scol], A + arow1 * K + kk + scol);
    gld16(&Bs[srow * 32 + scol],        Bt + brow0 * K + kk + scol);
    gld16(&Bs[(64 + srow) * 32 + scol], Bt + brow1 * K + kk + scol);
    __syncthreads();
    short8 af[4], bfr[4];
#pragma unroll
    for (int mt = 0; mt < 4; ++mt)
      af[mt] = *(const short8*)&As[(wm + mt * 16 + l16) * 32 + quad * 8];
#pragma unroll
    for (int nt = 0; nt < 4; ++nt)
      bfr[nt] = *(const short8*)&Bs[(wn + nt * 16 + l16) * 32 + quad * 8];
#pragma unroll
    for (int mt = 0; mt < 4; ++mt)
#pragma unroll
      for (int nt = 0; nt < 4; ++nt)
        acc[mt][nt] = __builtin_amdgcn_mfma_f32_16x16x32_bf16(af[mt], bfr[nt], acc[mt][nt], 0, 0, 0);
  }
#pragma unroll
  for (int mt = 0; mt < 4; ++mt) {
#pragma unroll
    for (int nt = 0; nt < 4; ++nt) {
#pragma unroll
      for (int r = 0; r < 4; ++r) {
        int m = m0 + wm + mt * 16 + quad * 4 + r;
        int n = n0 + wn + nt * 16 + l16;
        float v = acc[mt][nt][r];
        if (ADD_BIAS) v += bias[n];
        if (OUT_BF16) ((u16*)Cout)[(size_t)m * N + n] = f2bf(v);
        else          ((float*)Cout)[(size_t)m * N + n] = v;
      }
    }
  }
}

// ---------------- 3-stage pipelined persistent scan, 192 WGs --------------------
// grp 0 (WG 0..63):    L0  — h1 recurrence (gx0 precomputed).
// grp 1 (WG 64..127):  GX1 — gx1[t] = h1[t+1] @ Wih1^T into full buffer.
// grp 2 (WG 128..191): L1  — h2 recurrence from gx1 + Whh1.
// Sync: per-(WG,wave) flags. flag[wg*4+w] = v means that wave's (b=4w..4w+3,
// j=16wg..16wg+16) slice of slot v-1 is visible at the memory-side IF (producer
// drains vmcnt of its write-through stores before the relaxed flag store).
// Consumer wave polls exactly the 64 producer-wave flags covering its K-chunk
// (flags[wave*64+lane]); bulk data then moves via cached global_load_lds — the
// lines are first-touched only after the flag confirms, so no stale copies.
__global__ __launch_bounds__(256, 1)
void fused_scan_kernel(const u16* __restrict__ gx0,
                       u16* __restrict__ h1p, u16* __restrict__ h2p,
                       u16* __restrict__ gx1buf,   // [t][wg][b][3*16] u16, 1536B/(t,wg)
                       const u16* __restrict__ Whh0, const u16* __restrict__ Wih1,
                       const u16* __restrict__ Whh1,
                       const float* __restrict__ bih0, const float* __restrict__ bhh0,
                       const float* __restrict__ bih1, const float* __restrict__ bhh1,
                       unsigned* __restrict__ flags0, unsigned* __restrict__ flagsG,
                       unsigned* __restrict__ flags1) {
  const int tid = threadIdx.x;
  const int wave = tid >> 6, lane = tid & 63;
  const int quad = lane >> 4, l16 = lane & 15;
  const int kbase = wave * 256;
  const int b = tid >> 4, c = tid & 15;     // ownership for reduce/gates/store
  const int grp = blockIdx.x >> 6;
  const int wg = blockIdx.x & 63, j0 = wg * 16;
  const int halfsel = lane >> 5, koff = (lane & 31) * 8;

  // LDS: per-wave K-chunk staging, rows pair-packed (2x512B) + 16B pad per pair.
  __shared__ u16 hsw[4][8 * 520];
  __shared__ float part[2][4][3][256];
  __shared__ float biasS[2][3][16];

  const u16* W = (grp == 0) ? Whh0 : (grp == 1) ? Wih1 : Whh1;
  short8 wf[3][8];
#pragma unroll
  for (int g = 0; g < 3; ++g)
#pragma unroll
    for (int s = 0; s < 8; ++s)
      wf[g][s] = *(const short8*)&W[(size_t)(g * 1024 + j0 + l16) * 1024 + kbase + s * 32 + quad * 8];

  if (grp != 1 && tid < 96) {
    int a = tid / 48, rem = tid % 48, g = rem >> 4, jl = rem & 15;
    const float* bi = (grp == 0) ? (a ? bhh0 : bih0) : (a ? bhh1 : bih1);
    biasS[a][g][jl] = bi[g * 1024 + j0 + jl];
  }

  // init: L0/L1 zero their own (b,j) slice of slot 0, drain, publish flag=1
  if (grp != 1) {
    u16* hp = (grp == 0) ? h1p : h2p;
    unsigned* fl = (grp == 0) ? flags0 : flags1;
    if ((tid & 1) == 0)
      stA((unsigned*)(hp + ((size_t)b * TP1 + 0) * HDIM + j0 + c), 0u);
    wait_vm0();
    if (lane == 0) stA(&fl[wg * 4 + wave], 1u);
  }

  float hprev = 0.f;

  for (int t = 0; t < T_SEQ; ++t) {
    const int pb = t & 1;
    unsigned q0, q1, q2;           // gate inputs (gx values)

    if (grp == 0) {
      // prefetch own gx0 (no flag dependency)
      const u16* gxp = gx0 + ((size_t)(b * T_SEQ + t)) * NG + j0 + c;
      q0 = gxp[0]; q1 = gxp[1024]; q2 = gxp[2048];
      // poll h1[t] producers for this wave's K-chunk
      unsigned need = (unsigned)(t + 1);
      const unsigned* fp = flags0 + wave * 64 + lane;
      for (;;) { unsigned v = ldA(fp); if (__ballot(v >= need) == ~0ull) break; }
      __asm__ volatile("" ::: "memory");
#pragma unroll
      for (int i = 0; i < 8; ++i)
        gld16(&hsw[wave][i * 520],
              h1p + ((size_t)(2 * i + halfsel) * TP1 + t) * HDIM + kbase + koff);
    } else if (grp == 1) {
      // GX1: needs h1 slot t+1  (= L0 step t done -> flags0 >= t+2)
      unsigned need = (unsigned)(t + 2);
      const unsigned* fp = flags0 + wave * 64 + lane;
      for (;;) { unsigned v = ldA(fp); if (__ballot(v >= need) == ~0ull) break; }
      __asm__ volatile("" ::: "memory");
#pragma unroll
      for (int i = 0; i < 8; ++i)
        gld16(&hsw[wave][i * 520],
              h1p + ((size_t)(2 * i + halfsel) * TP1 + t + 1) * HDIM + kbase + koff);
    } else {
      // L1: needs gx1[t] (flagsG >= t+1 for own b-range) and h2 slot t (flags1 >= t+1)
      unsigned need = (unsigned)(t + 1);
      const unsigned* fp = flags1 + wave * 64 + lane;
      const unsigned* fg = flagsG + wg * 4 + wave;
      for (;;) {
        unsigned v = ldA(fp), g = ldA(fg);
        if (__ballot((v >= need) && (g >= need)) == ~0ull) break;
      }
      __asm__ volatile("" ::: "memory");
      const u16* gq = gx1buf + (((size_t)t * 64 + wg) * 16 + b) * 48 + c;
      q0 = gq[0]; q1 = gq[16]; q2 = gq[32];
#pragma unroll
      for (int i = 0; i < 8; ++i)
        gld16(&hsw[wave][i * 520],
              h2p + ((size_t)(2 * i + halfsel) * TP1 + t) * HDIM + kbase + koff);
    }

    wait_vm0();   // staged LDS (and gx loads) ready

    f32x4 a0 = {0.f,0.f,0.f,0.f}, a1 = {0.f,0.f,0.f,0.f}, a2 = {0.f,0.f,0.f,0.f};
#pragma unroll
    for (int s = 0; s < 8; ++s) {
      short8 afr = *(const short8*)&hsw[wave][(l16 >> 1) * 520 + (l16 & 1) * 256 + s * 32 + quad * 8];
      a0 = __builtin_amdgcn_mfma_f32_16x16x32_bf16(afr, wf[0][s], a0, 0, 0, 0);
      a1 = __builtin_amdgcn_mfma_f32_16x16x32_bf16(afr, wf[1][s], a1, 0, 0, 0);
      a2 = __builtin_amdgcn_mfma_f32_16x16x32_bf16(afr, wf[2][s], a2, 0, 0, 0);
    }
#pragma unroll
    for (int r = 0; r < 4; ++r) {
      int o = (quad * 4 + r) * 16 + l16;
      part[pb][wave][0][o] = a0[r];
      part[pb][wave][1][o] = a1[r];
      part[pb][wave][2][o] = a2[r];
    }
    __syncthreads();   // the single per-step barrier

    float s0 = part[pb][0][0][tid] + part[pb][1][0][tid] + part[pb][2][0][tid] + part[pb][3][0][tid];
    float s1 = part[pb][0][1][tid] + part[pb][1][1][tid] + part[pb][2][1][tid] + part[pb][3][1][tid];
    float s2 = part[pb][0][2][tid] + part[pb][1][2][tid] + part[pb][2][2][tid] + part[pb][3][2][tid];

    if (grp == 1) {
      // gx1 slices out, pair-packed write-through; publish after drain
      unsigned m0 = (unsigned)f2bf(s0), m1 = (unsigned)f2bf(s1), m2 = (unsigned)f2bf(s2);
      unsigned o0 = __shfl_xor(m0, 1), o1 = __shfl_xor(m1, 1), o2 = __shfl_xor(m2, 1);
      if ((tid & 1) == 0) {
        unsigned* dst = (unsigned*)(gx1buf + (((size_t)t * 64 + wg) * 16 + b) * 48 + c);
        stA(dst,      m0 | (o0 << 16));
        stA(dst + 8,  m1 | (o1 << 16));
        stA(dst + 16, m2 | (o2 << 16));
      }
      wait_vm0();
      if (lane == 0) stA(&flagsG[wg * 4 + wave], (unsigned)(t + 1));
      __asm__ volatile("" ::: "memory");
    } else {
      float ghr = s0 + biasS[1][0][c];
      float ghz = s1 + biasS[1][1][c];
      float ghn = s2 + biasS[1][2][c];
      float xr = bf2f(q0) + biasS[0][0][c] + ghr;
      float xz = bf2f(q1) + biasS[0][1][c] + ghz;
      float xn = bf2f(q2) + biasS[0][2][c];
      float r_ = 1.f / (1.f + __expf(-xr));
      float z_ = 1.f / (1.f + __expf(-xz));
      float pre = fminf(fmaxf(xn + r_ * ghn, -15.f), 15.f);
      float e2 = __expf(2.f * pre);
      float n_ = (e2 - 1.f) / (e2 + 1.f);
      float hn = (1.f - z_) * n_ + z_ * hprev;
      hprev = hn;

      u16* hp = (grp == 0) ? h1p : h2p;
      unsigned* fl = (grp == 0) ? flags0 : flags1;
      unsigned mine = (unsigned)f2bf(hn);
      unsigned other = __shfl_xor(mine, 1);
      if ((tid & 1) == 0)
        stA((unsigned*)(hp + ((size_t)b * TP1 + t + 1) * HDIM + j0 + c), mine | (other << 16));
      wait_vm0();
      if (lane == 0) stA(&fl[wg * 4 + wave], (unsigned)(t + 2));
      __asm__ volatile("" ::: "memory");
    }
  }
}

// ---------------- log_softmax over axis=1 (T): grid (16 b, 8 cgroups) ----------
__global__ void logsoftmax_kernel(float* __restrict__ out) {
  int b = blockIdx.x, cg = blockIdx.y;
  int ci = threadIdx.x & 15, ts = threadIdx.x >> 4;
  int c = cg * 16 + ci;
  float m = -1e30f, s = 0.f;
  for (int t = ts; t < T_SEQ; t += 16) {
    float v = out[((size_t)b * T_SEQ + t) * 128 + c];
    if (v > m) { s = s * __expf(m - v) + 1.f; m = v; }
    else s += __expf(v - m);
  }
  __shared__ float mS[16][16], sS[16][16];
  mS[ts][ci] = m; sS[ts][ci] = s;
  __syncthreads();
  if (ts == 0) {
    float M = mS[0][ci], S = sS[0][ci];
#pragma unroll
    for (int k = 1; k < 16; ++k) {
      float m2 = mS[k][ci], s2 = sS[k][ci];
      float nm = fmaxf(M, m2);
      S = S * __expf(M - nm) + s2 * __expf(m2 - nm);
      M = nm;
    }
    sS[0][ci] = M + logf(S);
  }
  __syncthreads();
  float lsd = sS[0][ci];
  for (int t = ts; t < T_SEQ; t += 16) {
    size_t i = ((size_t)b * T_SEQ + t) * 128 + c;
    out[i] -= lsd;
  }
}

// --------------------------------------------------------------------------------
extern "C" void kernel_launch(void* const* d_in, const int* in_sizes, int n_in,
                              void* d_out, int out_size, void* d_ws, size_t ws_size,
                              hipStream_t stream) {
  const int*   tokens = (const int*)d_in[0];
  const float* emb  = (const float*)d_in[1];
  const float* Wih0 = (const float*)d_in[2];
  const float* Whh0 = (const float*)d_in[3];
  const float* bih0 = (const float*)d_in[4];
  const float* bhh0 = (const float*)d_in[5];
  const float* Wih1 = (const float*)d_in[6];
  const float* Whh1 = (const float*)d_in[7];
  const float* bih1 = (const float*)d_in[8];
  const float* bhh1 = (const float*)d_in[9];
  const float* Wlin = (const float*)d_in[10];
  const float* blin = (const float*)d_in[11];
  float* out = (float*)d_out;

  uint8_t* ws = (uint8_t*)d_ws;
  size_t off = 0;
  auto alloc = [&](size_t bytes) -> void* {
    void* p = ws + off;
    off += (bytes + 255) & ~(size_t)255;
    return p;
  };
  u16* h1p    = (u16*)alloc((size_t)16 * TP1 * HDIM * 2);   // 33.6 MB
  u16* h2p    = (u16*)alloc((size_t)16 * TP1 * HDIM * 2);   // 33.6 MB (x-buf pre-scan)
  u16* gx0buf = (u16*)alloc((size_t)16384 * NG * 2);        // 101 MB
  u16* gx1buf = (u16*)alloc((size_t)T_SEQ * 64 * 16 * 48 * 2); // 101 MB
  u16* wih0b = (u16*)alloc((size_t)NG * HDIM * 2);
  u16* whh0b = (u16*)alloc((size_t)NG * HDIM * 2);
  u16* wih1b = (u16*)alloc((size_t)NG * HDIM * 2);
  u16* whh1b = (u16*)alloc((size_t)NG * HDIM * 2);
  u16* wlinb = (u16*)alloc((size_t)128 * HDIM * 2);
  unsigned* flags = (unsigned*)alloc(3072);  // flags0 | flagsG | flags1 (256 each)

  cast5_kernel<<<dim3(12416), dim3(256), 0, stream>>>(
      Wih0, Whh0, Wih1, Whh1, Wlin, wih0b, whh0b, wih1b, whh1b, wlinb, flags);
  // x (bf16) into h2p region (dead after gx0 GEMM; scan rewrites all slots)
  gather_cast_kernel<<<dim3(16384), dim3(256), 0, stream>>>(tokens, emb, h2p);
  // gx0 = x @ W_ih0^T
  gemm_bt<true, false, false><<<dim3(128, 24), dim3(256), 0, stream>>>(
      h2p, wih0b, gx0buf, nullptr, 16384, NG);
  // 3-stage pipelined scan: L0 | GX1 | L1
  fused_scan_kernel<<<dim3(192), dim3(256), 0, stream>>>(
      gx0buf, h1p, h2p, gx1buf, whh0b, wih1b, whh1b,
      bih0, bhh0, bih1, bhh1, flags, flags + 256, flags + 512);
  // logits = h2 @ W_lin^T + b_lin -> d_out (fp32)
  gemm_bt<false, true, true><<<dim3(128, 1), dim3(256), 0, stream>>>(
      h2p, wlinb, out, blin, 16384, 128);
  // log_softmax over T, in place
  logsoftmax_kernel<<<dim3(16, 8), dim3(256), 0, stream>>>(out);
}